// Round 5
// baseline (233.938 us; speedup 1.0000x reference)
//
#include <hip/hip_runtime.h>

// Problem constants (fixed by reference setup_inputs)
#define B_    8
#define C_    16
#define T_    2000
#define F_    128
#define F4_   32           // float4 per full feature row
#define POOL_ 10
#define T1_   200          // T_/POOL_ (exact, no tail)
#define BC_   128          // B_*C_
#define EPS_  1e-5f

#define G_      20         // pooled blocks per chunk
#define NCHUNK_ 10         // T1_/G_
#define QF4_    8          // float4 per 32-feature quarter row

// ---------------------------------------------------------------------------
// LDS-only barrier: drains lgkmcnt (orders sS/runS publishes), NOT vmcnt, so
// prefetch loads and streaming stores stay in flight across it.
// ---------------------------------------------------------------------------
static __device__ __forceinline__ void wg_barrier_lds_only()
{
    __builtin_amdgcn_sched_barrier(0);
    asm volatile("s_waitcnt lgkmcnt(0)\n\ts_barrier" ::: "memory");
    __builtin_amdgcn_sched_barrier(0);
}

// ---------------------------------------------------------------------------
// Fused causal instance-norm, distance-2 prefetch (round-4 rotation FIXED).
// Round-4 bug: refilled buf[c%3] with chunk c+2; chunk c+2 belongs in
// buf[(c+2)%3] -> buf[2] was never written and was consumed at c=2.
// Correct rotation: consume buf[c%3], refill buf[(c+2)%3] (free since its
// last consumption was iteration c-1). Loop fully unrolled -> all indices
// compile-time constant (no scratch).
// ---------------------------------------------------------------------------
__global__ __launch_bounds__(320) void fused_cumnorm(
    const float4* __restrict__ x4, float4* __restrict__ out4)
{
    const int tid = (int)threadIdx.x;
    const int bc  = (int)blockIdx.x >> 2;
    const int q   = (int)blockIdx.x & 3;
    const int g   = tid >> 4;           // 0..19 : pooled block within chunk
    const int kp  = (tid >> 3) & 1;     // 0..1  : row parity within block
    const int f4  = tid & 7;            // 0..7  : float4 column within quarter

    __shared__ float4 sS  [2][G_][QF4_];   // per-chunk block sums (parity dbuf)
    __shared__ float4 sS2 [2][G_][QF4_];
    __shared__ float4 runS [2][QF4_];      // running totals (parity dbuf)
    __shared__ float4 runS2[2][QF4_];

    const size_t tbase = (size_t)bc * T_ * F4_ + (size_t)(g * POOL_ + kp) * F4_
                       + (size_t)q * QF4_ + (size_t)f4;
    const float4* __restrict__ pc = x4   + tbase;
    float4*       __restrict__ qc = out4 + tbase;

    const int RS = 2 * F4_;             // 64  : same-parity row stride
    const int CS = G_ * POOL_ * F4_;    // 6400: chunk stride

    // 3-set rotation: chunk c lives in buf[c%3].
    float4 buf[3][5];

    // prologue: issue chunks 0 and 1 (2 chunks in flight)
#pragma unroll
    for (int i = 0; i < 5; ++i) buf[0][i] = pc[i * RS];
    {
        const float4* p1 = pc + CS;
#pragma unroll
        for (int i = 0; i < 5; ++i) buf[1][i] = p1[i * RS];
    }

    if (tid < QF4_) {
        runS [0][tid] = make_float4(0.f, 0.f, 0.f, 0.f);
        runS2[0][tid] = make_float4(0.f, 0.f, 0.f, 0.f);
    }
    // (visible after the first in-loop barrier, before any read)

#pragma unroll
    for (int c = 0; c < NCHUNK_; ++c) {
        const int p   = c & 1;
        const int cur = c % 3;          // consumed this iteration
        const int nxt = (c + 2) % 3;    // refilled this iteration (chunk c+2)

        const float4 v0 = buf[cur][0], v1 = buf[cur][1], v2 = buf[cur][2],
                     v3 = buf[cur][3], v4 = buf[cur][4];

        // ---- partial block sums over this thread's 5 rows
        float4 s, s2;
        s.x = ((v0.x + v1.x) + (v2.x + v3.x)) + v4.x;
        s.y = ((v0.y + v1.y) + (v2.y + v3.y)) + v4.y;
        s.z = ((v0.z + v1.z) + (v2.z + v3.z)) + v4.z;
        s.w = ((v0.w + v1.w) + (v2.w + v3.w)) + v4.w;
        s2.x = v0.x*v0.x; s2.x = fmaf(v1.x,v1.x,s2.x); s2.x = fmaf(v2.x,v2.x,s2.x); s2.x = fmaf(v3.x,v3.x,s2.x); s2.x = fmaf(v4.x,v4.x,s2.x);
        s2.y = v0.y*v0.y; s2.y = fmaf(v1.y,v1.y,s2.y); s2.y = fmaf(v2.y,v2.y,s2.y); s2.y = fmaf(v3.y,v3.y,s2.y); s2.y = fmaf(v4.y,v4.y,s2.y);
        s2.z = v0.z*v0.z; s2.z = fmaf(v1.z,v1.z,s2.z); s2.z = fmaf(v2.z,v2.z,s2.z); s2.z = fmaf(v3.z,v3.z,s2.z); s2.z = fmaf(v4.z,v4.z,s2.z);
        s2.w = v0.w*v0.w; s2.w = fmaf(v1.w,v1.w,s2.w); s2.w = fmaf(v2.w,v2.w,s2.w); s2.w = fmaf(v3.w,v3.w,s2.w); s2.w = fmaf(v4.w,v4.w,s2.w);

        // ---- fold the kp pair (lanes l <-> l^8 within the wave)
        s.x  += __shfl_xor(s.x , 8);
        s.y  += __shfl_xor(s.y , 8);
        s.z  += __shfl_xor(s.z , 8);
        s.w  += __shfl_xor(s.w , 8);
        s2.x += __shfl_xor(s2.x, 8);
        s2.y += __shfl_xor(s2.y, 8);
        s2.z += __shfl_xor(s2.z, 8);
        s2.w += __shfl_xor(s2.w, 8);

        // ---- publish block sums
        if (kp == 0) { sS[p][g][f4] = s; sS2[p][g][f4] = s2; }

        wg_barrier_lds_only();   // LDS visibility only; vmem NOT drained

        // ---- causal inclusive prefix, fixed 20 trips, predicated add
        float4 acc  = runS [p][f4];
        float4 acc2 = runS2[p][f4];
#pragma unroll 4
        for (int j = 0; j < G_; ++j) {
            const float4 aj  = sS [p][j][f4];
            const float4 a2j = sS2[p][j][f4];
            if (j <= g) {
                acc.x  += aj.x;  acc.y  += aj.y;  acc.z  += aj.z;  acc.w  += aj.w;
                acc2.x += a2j.x; acc2.y += a2j.y; acc2.z += a2j.z; acc2.w += a2j.w;
            }
        }

        const float inv = 1.0f / (float)((c * G_ + g + 1) * POOL_);
        float4 mean, rstd;
        mean.x = acc.x * inv; rstd.x = rsqrtf(fmaf(-mean.x, mean.x, acc2.x * inv) + EPS_);
        mean.y = acc.y * inv; rstd.y = rsqrtf(fmaf(-mean.y, mean.y, acc2.y * inv) + EPS_);
        mean.z = acc.z * inv; rstd.z = rsqrtf(fmaf(-mean.z, mean.z, acc2.z * inv) + EPS_);
        mean.w = acc.w * inv; rstd.w = rsqrtf(fmaf(-mean.w, mean.w, acc2.w * inv) + EPS_);

        // ---- normalize held registers, store (same addresses as loads)
        float4 o;
        o.x = (v0.x - mean.x) * rstd.x; o.y = (v0.y - mean.y) * rstd.y;
        o.z = (v0.z - mean.z) * rstd.z; o.w = (v0.w - mean.w) * rstd.w;
        qc[0] = o;
        o.x = (v1.x - mean.x) * rstd.x; o.y = (v1.y - mean.y) * rstd.y;
        o.z = (v1.z - mean.z) * rstd.z; o.w = (v1.w - mean.w) * rstd.w;
        qc[RS] = o;
        o.x = (v2.x - mean.x) * rstd.x; o.y = (v2.y - mean.y) * rstd.y;
        o.z = (v2.z - mean.z) * rstd.z; o.w = (v2.w - mean.w) * rstd.w;
        qc[2*RS] = o;
        o.x = (v3.x - mean.x) * rstd.x; o.y = (v3.y - mean.y) * rstd.y;
        o.z = (v3.z - mean.z) * rstd.z; o.w = (v3.w - mean.w) * rstd.w;
        qc[3*RS] = o;
        o.x = (v4.x - mean.x) * rstd.x; o.y = (v4.y - mean.y) * rstd.y;
        o.z = (v4.z - mean.z) * rstd.z; o.w = (v4.w - mean.w) * rstd.w;
        qc[4*RS] = o;

        // ---- group G-1's inclusive prefix IS the next running total
        if (g == G_ - 1 && kp == 0) {
            runS [p ^ 1][f4] = acc;
            runS2[p ^ 1][f4] = acc2;
        }
        // race audit unchanged from round 3: sS parity-disjoint; runS[p^1]
        // written pre-(writer's)-barrier arrival, read after next barrier.

        // ---- refill the FREE set (last consumed at c-1) with chunk c+2
        if (c + 2 < NCHUNK_) {
            const float4* pn = pc + 2 * CS;
#pragma unroll
            for (int i = 0; i < 5; ++i) buf[nxt][i] = pn[i * RS];
        }

        pc += CS; qc += CS;
    }
}

extern "C" void kernel_launch(void* const* d_in, const int* in_sizes, int n_in,
                              void* d_out, int out_size, void* d_ws, size_t ws_size,
                              hipStream_t stream)
{
    (void)in_sizes; (void)n_in; (void)d_ws; (void)ws_size; (void)out_size;
    // 128 bc x 4 feature-quarters = 512 WGs (2/CU), 320 threads (5 waves)
    fused_cumnorm<<<BC_ * 4, 320, 0, stream>>>(
        (const float4*)d_in[0], (float4*)d_out);
}